// Round 1
// baseline (520.708 us; speedup 1.0000x reference)
//
#include <hip/hip_runtime.h>
#include <hip/hip_bf16.h>

// Single-head self-attention, B=8 S=2048 E=768, fp32 in/out.
// R5: replace the m97-style 128x128 2-barrier GEMM (struct. ceiling ~560 TF here)
//     with the verified 256x256 8-phase counted-vmcnt template:
//   - BM=BN=256, BK=64, 512 thr (8 waves, 2Mx4N), per-wave C = 128x64
//   - LDS 128 KiB: 2 x (A,B) x 256 x 64 bf16, double-buffered K-tiles
//   - read-side XOR-8 chunk swizzle (bank-balanced ds_read_b128), realized by
//     pre-swizzled per-lane GLOBAL source + linear global_load_lds dest (m173)
//   - 8 phases / 2 K-tiles per iter; one half-tile granule staged per phase;
//     vmcnt(6) only at phases 4/8 (3 granules in flight, never drain to 0)
//   - s_setprio(1) around each 16-MFMA cluster (T5, only pays on 8-phase)
//   - bijective XCD swizzle of flattened block id (all grids % 8 == 0)
// Numerics identical to R4 (same MFMA, same k-order, same epilogue).

using short8  = __attribute__((ext_vector_type(8))) short;
using floatx4 = __attribute__((ext_vector_type(4))) float;

typedef const __attribute__((address_space(1))) unsigned short* gas_us;
typedef __attribute__((address_space(3))) unsigned short* las_us;

__device__ __forceinline__ float bf2f(unsigned short u){
  union { unsigned int i; float f; } v; v.i = ((unsigned int)u) << 16; return v.f;
}
__device__ __forceinline__ unsigned short f2bf(float f){
  union { float f; unsigned int i; } v; v.f = f;
  unsigned int r = v.i + 0x7fffu + ((v.i >> 16) & 1u);   // RNE
  return (unsigned short)(r >> 16);
}

// ---------------- prep kernels ----------------

__global__ __launch_bounds__(256) void cast_f32_bf16(const float* __restrict__ in,
                                                     unsigned short* __restrict__ out,
                                                     long n){
  long i = ((long)blockIdx.x * 256 + threadIdx.x) * 4;
  if (i + 3 < n) {
    float4 v = *(const float4*)(in + i);
    uint2 o;
    o.x = (unsigned int)f2bf(v.x) | ((unsigned int)f2bf(v.y) << 16);
    o.y = (unsigned int)f2bf(v.z) | ((unsigned int)f2bf(v.w) << 16);
    *(uint2*)(out + i) = o;
  }
}

// W [n x n] fp32 row-major -> Wt [n x n] bf16, Wt[f][e] = W[e][f]
__global__ __launch_bounds__(256) void transpose_cast_w(const float* __restrict__ W,
                                                        unsigned short* __restrict__ Wt,
                                                        int n){
  __shared__ float tile[64][65];
  int bx = blockIdx.x * 64;     // f base
  int by = blockIdx.y * 64;     // e base
  int tx = threadIdx.x & 63;
  int ty = threadIdx.x >> 6;    // 0..3
  #pragma unroll
  for (int r = ty; r < 64; r += 4)
    tile[r][tx] = W[(long)(by + r) * n + bx + tx];
  __syncthreads();
  #pragma unroll
  for (int r = ty; r < 64; r += 4)
    Wt[(long)(bx + r) * n + by + tx] = f2bf(tile[tx][r]);
}

// ---------------- 256x256 8-phase MFMA GEMM ----------------
// C[m,n] = alpha * sum_k A[m,k]*Bt[n,k]  (+ bias)
// A  : bf16 [M,K] row-major (batch stride sA elements)
// Bt : bf16 [N,K] row-major (batch stride sB elements)
// C  : bf16 or fp32, ldc leading dim (batch stride sC elements)
// Requires: M,N multiples of 256; K multiple of 128. No bounds checks.

__global__ __launch_bounds__(512, 2) void gemm256(
    const unsigned short* __restrict__ A,
    const unsigned short* __restrict__ Bt,
    void* __restrict__ Cout,
    const float* __restrict__ bias,
    int M, int N, int K, int ldc,
    long sA, long sB, long sC,
    float alpha, int bias_mode, int out_fp32)
{
  // --- XCD-aware bijective swizzle of flattened block id (nwg % 8 == 0) ---
  const int gx = gridDim.x, gy = gridDim.y;
  const int nxy = gx * gy;
  const int nwg = nxy * (int)gridDim.z;
  int flat = (int)blockIdx.x + gx * (int)blockIdx.y + nxy * (int)blockIdx.z;
  if (!(nwg & 7)) flat = (flat & 7) * (nwg >> 3) + (flat >> 3);
  const int bz  = flat / nxy;
  const int rxy = flat - bz * nxy;
  const int by  = rxy / gx;
  const int bx  = rxy - by * gx;

  A  += (long)bz * sA;
  Bt += (long)bz * sB;

  // double-buffered K-tiles: [2][256 rows][64 k] bf16 each, 64 KiB per operand
  __shared__ __align__(16) unsigned short Asm[2 * 256 * 64];
  __shared__ __align__(16) unsigned short Bsm[2 * 256 * 64];

  const int tid  = threadIdx.x;
  const int l    = tid & 63;
  const int wv   = tid >> 6;        // 0..7
  const int wm   = wv >> 2;         // 0..1  (M half of block)
  const int wn   = wv & 3;          // 0..3  (N quarter)
  const int la   = l & 15;
  const int quad = l >> 4;
  const int c0   = quad ^ (l & 7);  // swizzled chunk for kstep 0 (row&7 == la&7)

  const long m0 = (long)by * 256;
  const long n0 = (long)bx * 256;
  const long Kl = K;

  // staging geometry: granule g of a 256-row tile = rows {g*64..g*64+63} U {128+g*64..}
  // wave wv, instr j stages 8 rows starting at r_loc = wv*16 + j*8 within granule.
  const int r8  = l >> 3;                 // 0..7  (row within 8-row group)
  const int cg  = (l & 7) ^ r8;           // pre-swizzled global chunk for this lane
  const int st0 = wv * 16, st1 = wv * 16 + 8;
  const int ar0 = (st0 >> 6) * 128 + (st0 & 63);   // actual row base, j=0, g=0
  const int ar1 = (st1 >> 6) * 128 + (st1 & 63);   // actual row base, j=1, g=0

  const unsigned short* sA0 = A  + (m0 + ar0 + r8) * Kl + cg * 8;
  const unsigned short* sA1 = A  + (m0 + ar1 + r8) * Kl + cg * 8;
  const unsigned short* sB0 = Bt + (n0 + ar0 + r8) * Kl + cg * 8;
  const unsigned short* sB1 = Bt + (n0 + ar1 + r8) * Kl + cg * 8;

  las_us dA0 = (las_us)&Asm[ar0 * 64];
  las_us dA1 = (las_us)&Asm[ar1 * 64];
  las_us dB0 = (las_us)&Bsm[ar0 * 64];
  las_us dB1 = (las_us)&Bsm[ar1 * 64];

  const short8* A8 = (const short8*)Asm;   // tile stride 2048 short8
  const short8* B8 = (const short8*)Bsm;
  const int rA = (wm * 128 + la) * 8;
  const int rB = (wn * 64  + la) * 8;

  floatx4 acc[8][4];
  #pragma unroll
  for (int i = 0; i < 8; i++)
    #pragma unroll
    for (int j = 0; j < 4; j++)
      #pragma unroll
      for (int r = 0; r < 4; r++) acc[i][j][r] = 0.0f;

  short8 a[4][2], b0[2][2], b1[2][2];

  const int NT = K >> 6;   // K-tiles of 64; K % 128 == 0 so NT even
  const int NI = NT >> 1;

// stage one 128-row granule (2 x global_load_lds, 16B/lane, linear LDS dest)
#define STG(P0,P1,D0,D1,BO,G,KT) do{ const long _ko=(long)(G)*64*Kl+(long)(KT)*64; \
  __builtin_amdgcn_global_load_lds((gas_us)((P0)+_ko),(D0)+(BO)+(G)*4096,16,0,0);  \
  __builtin_amdgcn_global_load_lds((gas_us)((P1)+_ko),(D1)+(BO)+(G)*4096,16,0,0);}while(0)
// ds_read_b128 fragment loads; BO in short8 units (0 or 2048)
#define LDA(BO,MH) { _Pragma("unroll") for (int mf=0; mf<4; mf++){ \
    a[mf][0]=A8[(BO)+rA+((MH)*4+mf)*128+c0]; a[mf][1]=A8[(BO)+rA+((MH)*4+mf)*128+(c0^4)]; } }
#define LDB(DST,BO,NH) { _Pragma("unroll") for (int nf=0; nf<2; nf++){ \
    DST[nf][0]=B8[(BO)+rB+((NH)*2+nf)*128+c0]; DST[nf][1]=B8[(BO)+rB+((NH)*2+nf)*128+(c0^4)]; } }
// 16 MFMA: one C quadrant x K=64
#define MM(MH,NH,BB) { _Pragma("unroll") for (int mf=0; mf<4; mf++) _Pragma("unroll") for (int nf=0; nf<2; nf++){ \
    acc[(MH)*4+mf][(NH)*2+nf]=__builtin_amdgcn_mfma_f32_16x16x32_bf16(a[mf][0],BB[nf][0],acc[(MH)*4+mf][(NH)*2+nf],0,0,0); \
    acc[(MH)*4+mf][(NH)*2+nf]=__builtin_amdgcn_mfma_f32_16x16x32_bf16(a[mf][1],BB[nf][1],acc[(MH)*4+mf][(NH)*2+nf],0,0,0); } }
#define BAR   __builtin_amdgcn_s_barrier()
#define WLG0  asm volatile("s_waitcnt lgkmcnt(0)")
#define PRIO1 __builtin_amdgcn_s_setprio(1)
#define PRIO0 __builtin_amdgcn_s_setprio(0)

  // prologue: tile0 -> buf0 (4 granules), vmcnt(4), tile1 -> buf1 (3 granules), vmcnt(6)
  STG(sA0,sA1,dA0,dA1,0,0,0);
  STG(sB0,sB1,dB0,dB1,0,0,0);
  STG(sA0,sA1,dA0,dA1,0,1,0);
  STG(sB0,sB1,dB0,dB1,0,1,0);
  asm volatile("s_waitcnt vmcnt(4)");
  STG(sA0,sA1,dA0,dA1,16384,0,1);
  STG(sB0,sB1,dB0,dB1,16384,0,1);
  STG(sA0,sA1,dA0,dA1,16384,1,1);
  asm volatile("s_waitcnt vmcnt(6)");
  BAR;

  for (int i = 0; i < NI; i++) {
    const int t1 = 2*i + 1;                                  // always < NT
    const int t2 = (2*i + 2 < NT) ? 2*i + 2 : NT - 1;        // clamped prefetch
    const int t3 = (2*i + 3 < NT) ? 2*i + 3 : NT - 1;

    // P1: read buf0 A-h0 (8) + B-h0 (4); stage buf1 B-g1 (tile t1)
    LDA(0,0); LDB(b0,0,0);
    STG(sB0,sB1,dB0,dB1,16384,1,t1);
    asm volatile("s_waitcnt lgkmcnt(8)");
    BAR; WLG0; PRIO1; MM(0,0,b0); PRIO0; BAR;

    // P2: read buf0 B-h1 (4); stage buf0 A-g0 (tile t2)
    LDB(b1,0,1);
    STG(sA0,sA1,dA0,dA1,0,0,t2);
    BAR; WLG0; PRIO1; MM(0,1,b1); PRIO0; BAR;

    // P3: read buf0 A-h1 (8); stage buf0 B-g0 (tile t2)
    LDA(0,1);
    STG(sB0,sB1,dB0,dB1,0,0,t2);
    BAR; WLG0; PRIO1; MM(1,1,b1); PRIO0; BAR;

    // P4: no reads (b0 held); stage buf0 A-g1 (tile t2); counted vmcnt, never 0
    STG(sA0,sA1,dA0,dA1,0,1,t2);
    BAR; WLG0; PRIO1; MM(1,0,b0); PRIO0;
    asm volatile("s_waitcnt vmcnt(6)");
    BAR;

    // P5: read buf1 A-h0 + B-h0; stage buf0 B-g1 (tile t2)
    LDA(2048,0); LDB(b0,2048,0);
    STG(sB0,sB1,dB0,dB1,0,1,t2);
    asm volatile("s_waitcnt lgkmcnt(8)");
    BAR; WLG0; PRIO1; MM(0,0,b0); PRIO0; BAR;

    // P6: read buf1 B-h1; stage buf1 A-g0 (tile t3)
    LDB(b1,2048,1);
    STG(sA0,sA1,dA0,dA1,16384,0,t3);
    BAR; WLG0; PRIO1; MM(0,1,b1); PRIO0; BAR;

    // P7: read buf1 A-h1; stage buf1 B-g0 (tile t3)
    LDA(2048,1);
    STG(sB0,sB1,dB0,dB1,16384,0,t3);
    BAR; WLG0; PRIO1; MM(1,1,b1); PRIO0; BAR;

    // P8: no reads; stage buf1 A-g1 (tile t3); counted vmcnt
    STG(sA0,sA1,dA0,dA1,16384,1,t3);
    BAR; WLG0; PRIO1; MM(1,0,b0); PRIO0;
    asm volatile("s_waitcnt vmcnt(6)");
    BAR;
  }

  asm volatile("s_waitcnt vmcnt(0)");   // drain dangling clamped prefetches

#undef STG
#undef LDA
#undef LDB
#undef MM
#undef BAR
#undef WLG0
#undef PRIO1
#undef PRIO0

  // epilogue: C/D layout: n = la, m = quad*4 + reg   [measured m89/m91]
  float* Cf = (float*)Cout + (long)bz * sC;
  unsigned short* Ch = (unsigned short*)Cout + (long)bz * sC;
  #pragma unroll
  for (int mf = 0; mf < 8; mf++) {
    #pragma unroll
    for (int nf = 0; nf < 4; nf++) {
      #pragma unroll
      for (int r = 0; r < 4; r++) {
        long m = m0 + wm * 128 + mf * 16 + quad * 4 + r;
        long n = n0 + wn * 64  + nf * 16 + la;
        float v = acc[mf][nf][r] * alpha;
        if (bias_mode == 1)      v += bias[n];
        else if (bias_mode == 2) v += bias[m];
        long idx = m * (long)ldc + n;
        if (out_fp32) Cf[idx] = v;
        else          Ch[idx] = f2bf(v);
      }
    }
  }
}

// ---------------- row softmax (in-place, bf16) ----------------
__global__ __launch_bounds__(256) void softmax_rows(unsigned short* __restrict__ S, int cols){
  long row = blockIdx.x;
  unsigned short* p = S + row * (long)cols;
  int tid  = threadIdx.x;
  int wave = tid >> 6;
  int lane = tid & 63;

  uint4 raw = ((const uint4*)p)[tid];   // 8 bf16
  unsigned short* rs = (unsigned short*)&raw;
  float x[8];
  float mx = -1e30f;
  #pragma unroll
  for (int i = 0; i < 8; i++) { x[i] = bf2f(rs[i]); mx = fmaxf(mx, x[i]); }
  #pragma unroll
  for (int off = 32; off >= 1; off >>= 1) mx = fmaxf(mx, __shfl_xor(mx, off, 64));

  __shared__ float smax[4], ssum[4];
  if (lane == 0) smax[wave] = mx;
  __syncthreads();
  mx = fmaxf(fmaxf(smax[0], smax[1]), fmaxf(smax[2], smax[3]));

  float s = 0.0f;
  #pragma unroll
  for (int i = 0; i < 8; i++) { x[i] = __expf(x[i] - mx); s += x[i]; }
  #pragma unroll
  for (int off = 32; off >= 1; off >>= 1) s += __shfl_xor(s, off, 64);
  if (lane == 0) ssum[wave] = s;
  __syncthreads();
  s = ssum[0] + ssum[1] + ssum[2] + ssum[3];
  float inv = 1.0f / s;

  #pragma unroll
  for (int i = 0; i < 8; i++) rs[i] = f2bf(x[i] * inv);
  ((uint4*)p)[tid] = raw;
}

// ---------------- launch ----------------

extern "C" void kernel_launch(void* const* d_in, const int* in_sizes, int n_in,
                              void* d_out, int out_size, void* d_ws, size_t ws_size,
                              hipStream_t stream)
{
  const float* x  = (const float*)d_in[0];
  const float* Wq = (const float*)d_in[1];
  const float* bq = (const float*)d_in[2];
  const float* Wk = (const float*)d_in[3];
  const float* bk = (const float*)d_in[4];
  const float* Wv = (const float*)d_in[5];
  const float* bv = (const float*)d_in[6];
  const float* Wo = (const float*)d_in[7];
  const float* bo = (const float*)d_in[8];

  const int B = 8, S = 2048, E = 768;
  const long BS = (long)B * S;   // 16384

  char* ws = (char*)d_ws;
  unsigned short* x_bf = (unsigned short*)ws;  ws += BS * E * 2;     // 25.2 MB (also ctx)
  unsigned short* Wqt  = (unsigned short*)ws;  ws += (long)E * E * 2;
  unsigned short* Wkt  = (unsigned short*)ws;  ws += (long)E * E * 2;
  unsigned short* Wvt  = (unsigned short*)ws;  ws += (long)E * E * 2;
  unsigned short* Wot  = (unsigned short*)ws;  ws += (long)E * E * 2;
  unsigned short* Qb   = (unsigned short*)ws;  ws += BS * E * 2;     // 25.2 MB
  unsigned short* Kb   = (unsigned short*)ws;  ws += BS * E * 2;     // 25.2 MB
  unsigned short* Vt   = (unsigned short*)ws;  ws += BS * E * 2;     // 25.2 MB  [B][E][S]
  unsigned short* Sb   = (unsigned short*)ws;  ws += (long)B * S * S * 2; // 67.1 MB
  unsigned short* Cx   = x_bf;  // ctx aliases x_bf (x_bf dead after Vt gemm)

  if (ws_size < (size_t)((char*)ws - (char*)d_ws)) return;

  const float rsE = 1.0f / sqrtf((float)E);

  cast_f32_bf16<<<(int)((BS * E) / 1024), 256, 0, stream>>>(x, x_bf, BS * E);
  dim3 tg(E / 64, E / 64);
  transpose_cast_w<<<tg, 256, 0, stream>>>(Wq, Wqt, E);
  transpose_cast_w<<<tg, 256, 0, stream>>>(Wk, Wkt, E);
  transpose_cast_w<<<tg, 256, 0, stream>>>(Wv, Wvt, E);
  transpose_cast_w<<<tg, 256, 0, stream>>>(Wo, Wot, E);

  // Q = x@Wq, K = x@Wk : M=16384 N=768 K=768, grid 3x64 = 192 (%8==0)
  dim3 g1(E / 256, (int)(BS / 256), 1);
  gemm256<<<g1, 512, 0, stream>>>(x_bf, Wqt, Qb, bq, (int)BS, E, E, E, 0, 0, 0, 1.0f, 1, 0);
  gemm256<<<g1, 512, 0, stream>>>(x_bf, Wkt, Kb, bk, (int)BS, E, E, E, 0, 0, 0, 1.0f, 1, 0);

  // Vt[b][e][s] = Wv^T @ x^T : M=768 N=2048 K=768, grid 8x3x8 = 192
  dim3 gv(S / 256, E / 256, B);
  gemm256<<<gv, 512, 0, stream>>>(Wvt, x_bf, Vt, bv, E, S, E, S,
                                  0, (long)S * E, (long)E * S, 1.0f, 2, 0);

  // Sb = Q K^T / sqrt(E) : M=N=2048 K=768, grid 8x8x8 = 512 (one batch per XCD)
  dim3 gs(S / 256, S / 256, B);
  gemm256<<<gs, 512, 0, stream>>>(Qb, Kb, Sb, nullptr, S, S, E, S,
                                  (long)S * E, (long)S * E, (long)S * S, rsE, 0, 0);

  softmax_rows<<<(int)BS, 256, 0, stream>>>(Sb, S);

  // ctx = softmax(S) @ V : M=2048 N=768 K=2048, grid 3x8x8 = 192
  dim3 gp(E / 256, S / 256, B);
  gemm256<<<gp, 512, 0, stream>>>(Sb, Vt, Cx, nullptr, S, E, S, E,
                                  (long)S * S, (long)E * S, (long)S * E, 1.0f, 0, 0);

  // out = ctx @ Wo + bo (fp32 out)
  gemm256<<<g1, 512, 0, stream>>>(Cx, Wot, (float*)d_out, bo, (int)BS, E, E, E,
                                  0, 0, 0, 1.0f, 1, 1);
}

// Round 2
// 444.182 us; speedup vs baseline: 1.1723x; 1.1723x over previous
//
#include <hip/hip_runtime.h>
#include <hip/hip_bf16.h>

// Single-head self-attention, B=8 S=2048 E=768, fp32 in/out.
// R6: R5's 256x256 8-phase GEMM kept verbatim, but:
//   - Q,K,V projections fused into ONE gemm (N=2304, grid 576 = 2.25 rounds)
//     via concatenated transposed weights + concatenated bias; Q/K consumed
//     in-place from the fused buffer with lda/ldb=2304; V extracted to
//     Vt[B][E][S] by a 128x128 LDS transpose pass (~50 MB traffic).
//   - gemm256 is now template<TAG,BIASN,OUTF> so every GEMM role has a
//     distinct Kernel_Name in rocprof (top-5 aliasing made R5 counters
//     ambiguous); bias/out-dtype are compile-time.
//   - gemm gains lda/ldb (row strides) for the strided fused views.
// Schedule (8-phase, counted vmcnt(6), setprio, XCD swizzle) unchanged.

using short8  = __attribute__((ext_vector_type(8))) short;
using floatx4 = __attribute__((ext_vector_type(4))) float;

typedef const __attribute__((address_space(1))) unsigned short* gas_us;
typedef __attribute__((address_space(3))) unsigned short* las_us;

__device__ __forceinline__ float bf2f(unsigned short u){
  union { unsigned int i; float f; } v; v.i = ((unsigned int)u) << 16; return v.f;
}
__device__ __forceinline__ unsigned short f2bf(float f){
  union { float f; unsigned int i; } v; v.f = f;
  unsigned int r = v.i + 0x7fffu + ((v.i >> 16) & 1u);   // RNE
  return (unsigned short)(r >> 16);
}

// ---------------- prep kernels ----------------

__global__ __launch_bounds__(256) void cast_f32_bf16(const float* __restrict__ in,
                                                     unsigned short* __restrict__ out,
                                                     long n){
  long i = ((long)blockIdx.x * 256 + threadIdx.x) * 4;
  if (i + 3 < n) {
    float4 v = *(const float4*)(in + i);
    uint2 o;
    o.x = (unsigned int)f2bf(v.x) | ((unsigned int)f2bf(v.y) << 16);
    o.y = (unsigned int)f2bf(v.z) | ((unsigned int)f2bf(v.w) << 16);
    *(uint2*)(out + i) = o;
  }
}

// W [n x n] fp32 row-major -> Wt [n x n] bf16, Wt[f][e] = W[e][f]
__global__ __launch_bounds__(256) void transpose_cast_w(const float* __restrict__ W,
                                                        unsigned short* __restrict__ Wt,
                                                        int n){
  __shared__ float tile[64][65];
  int bx = blockIdx.x * 64;     // f base
  int by = blockIdx.y * 64;     // e base
  int tx = threadIdx.x & 63;
  int ty = threadIdx.x >> 6;    // 0..3
  #pragma unroll
  for (int r = ty; r < 64; r += 4)
    tile[r][tx] = W[(long)(by + r) * n + bx + tx];
  __syncthreads();
  #pragma unroll
  for (int r = ty; r < 64; r += 4)
    Wt[(long)(bx + r) * n + by + tx] = f2bf(tile[tx][r]);
}

// V slice of fused QKV buffer (row stride 2304) -> Vt[B][E][S] bf16.
// 128x128 LDS tile, ushort4 on both sides (256B/wave-instr each way).
__global__ __launch_bounds__(256) void vtrans(const unsigned short* __restrict__ Vsrc,
                                              unsigned short* __restrict__ Vt){
  __shared__ unsigned short t[128][129];
  const int s0 = blockIdx.x * 128;          // token tile (2048/128 = 16)
  const int e0 = blockIdx.y * 128;          // feature tile (768/128 = 6)
  const int b  = blockIdx.z;
  const int tx = threadIdx.x & 31;          // 32 lanes x ushort4
  const int ty = threadIdx.x >> 5;          // 0..7
  const unsigned short* src = Vsrc + (long)b * 2048 * 2304;
  #pragma unroll
  for (int r = ty; r < 128; r += 8) {
    ushort4 v = *(const ushort4*)&src[(long)(s0 + r) * 2304 + e0 + tx * 4];
    t[r][tx*4+0]=v.x; t[r][tx*4+1]=v.y; t[r][tx*4+2]=v.z; t[r][tx*4+3]=v.w;
  }
  __syncthreads();
  unsigned short* dst = Vt + (long)b * 768 * 2048;
  #pragma unroll
  for (int r = ty; r < 128; r += 8) {
    ushort4 v;
    v.x = t[tx*4+0][r]; v.y = t[tx*4+1][r];
    v.z = t[tx*4+2][r]; v.w = t[tx*4+3][r];
    *(ushort4*)&dst[(long)(e0 + r) * 2048 + s0 + tx * 4] = v;
  }
}

// ---------------- 256x256 8-phase MFMA GEMM ----------------
// C[m,n] = alpha * sum_k A[m,k]*Bt[n,k]  (+ bias[n])
// A  : bf16 [M x K] rows stride lda elements (batch stride sA)
// Bt : bf16 [N x K] rows stride ldb elements (batch stride sB)
// C  : bf16 or fp32 (OUTF), ldc leading dim (batch stride sC)
// Requires: M,N multiples of 256; K multiple of 128; grid.xyz product % 8 == 0.
// TAG only disambiguates Kernel_Name in rocprof: 0=qkv 1=qk 2=pv 3=o.

template<int TAG, int BIASN, int OUTF>
__global__ __launch_bounds__(512, 2) void gemm256(
    const unsigned short* __restrict__ A,
    const unsigned short* __restrict__ Bt,
    void* __restrict__ Cout,
    const float* __restrict__ bias,
    int M, int N, int K, int lda, int ldb, int ldc,
    long sA, long sB, long sC, float alpha)
{
  // --- XCD-aware bijective swizzle of flattened block id (nwg % 8 == 0) ---
  const int gx = gridDim.x, gy = gridDim.y;
  const int nxy = gx * gy;
  const int nwg = nxy * (int)gridDim.z;
  int flat = (int)blockIdx.x + gx * (int)blockIdx.y + nxy * (int)blockIdx.z;
  if (!(nwg & 7)) flat = (flat & 7) * (nwg >> 3) + (flat >> 3);
  const int bz  = flat / nxy;
  const int rxy = flat - bz * nxy;
  const int by  = rxy / gx;
  const int bx  = rxy - by * gx;

  A  += (long)bz * sA;
  Bt += (long)bz * sB;

  // double-buffered K-tiles: [2][256 rows][64 k] bf16 each, 64 KiB per operand
  __shared__ __align__(16) unsigned short Asm[2 * 256 * 64];
  __shared__ __align__(16) unsigned short Bsm[2 * 256 * 64];

  const int tid  = threadIdx.x;
  const int l    = tid & 63;
  const int wv   = tid >> 6;        // 0..7
  const int wm   = wv >> 2;         // 0..1  (M half of block)
  const int wn   = wv & 3;          // 0..3  (N quarter)
  const int la   = l & 15;
  const int quad = l >> 4;
  const int c0   = quad ^ (l & 7);  // swizzled chunk (row&7 == la&7)

  const long m0 = (long)by * 256;
  const long n0 = (long)bx * 256;
  const long ldaL = lda, ldbL = ldb;

  // staging: granule g of a 256-row tile = rows {g*64..+63} U {128+g*64..+63};
  // wave wv, instr j stages 8 rows at r_loc = wv*16 + j*8 within the granule.
  const int r8  = l >> 3;                 // 0..7
  const int cg  = (l & 7) ^ r8;           // pre-swizzled global chunk
  const int st0 = wv * 16, st1 = wv * 16 + 8;
  const int ar0 = (st0 >> 6) * 128 + (st0 & 63);
  const int ar1 = (st1 >> 6) * 128 + (st1 & 63);

  const unsigned short* sA0 = A  + (m0 + ar0 + r8) * ldaL + cg * 8;
  const unsigned short* sA1 = A  + (m0 + ar1 + r8) * ldaL + cg * 8;
  const unsigned short* sB0 = Bt + (n0 + ar0 + r8) * ldbL + cg * 8;
  const unsigned short* sB1 = Bt + (n0 + ar1 + r8) * ldbL + cg * 8;

  las_us dA0 = (las_us)&Asm[ar0 * 64];
  las_us dA1 = (las_us)&Asm[ar1 * 64];
  las_us dB0 = (las_us)&Bsm[ar0 * 64];
  las_us dB1 = (las_us)&Bsm[ar1 * 64];

  const short8* A8 = (const short8*)Asm;   // tile stride 2048 short8
  const short8* B8 = (const short8*)Bsm;
  const int rA = (wm * 128 + la) * 8;
  const int rB = (wn * 64  + la) * 8;

  floatx4 acc[8][4];
  #pragma unroll
  for (int i = 0; i < 8; i++)
    #pragma unroll
    for (int j = 0; j < 4; j++)
      #pragma unroll
      for (int r = 0; r < 4; r++) acc[i][j][r] = 0.0f;

  short8 a[4][2], b0[2][2], b1[2][2];

  const int NT = K >> 6;   // K % 128 == 0 so NT even
  const int NI = NT >> 1;

// stage one 128-row granule (2 x global_load_lds, 16B/lane, linear LDS dest)
#define STG(P0,P1,D0,D1,BO,G,KT,LD) do{ const long _ko=(long)(G)*64*(LD)+(long)(KT)*64; \
  __builtin_amdgcn_global_load_lds((gas_us)((P0)+_ko),(D0)+(BO)+(G)*4096,16,0,0);       \
  __builtin_amdgcn_global_load_lds((gas_us)((P1)+_ko),(D1)+(BO)+(G)*4096,16,0,0);}while(0)
// ds_read_b128 fragment loads; BO in short8 units (0 or 2048)
#define LDA(BO,MH) { _Pragma("unroll") for (int mf=0; mf<4; mf++){ \
    a[mf][0]=A8[(BO)+rA+((MH)*4+mf)*128+c0]; a[mf][1]=A8[(BO)+rA+((MH)*4+mf)*128+(c0^4)]; } }
#define LDB(DST,BO,NH) { _Pragma("unroll") for (int nf=0; nf<2; nf++){ \
    DST[nf][0]=B8[(BO)+rB+((NH)*2+nf)*128+c0]; DST[nf][1]=B8[(BO)+rB+((NH)*2+nf)*128+(c0^4)]; } }
// 16 MFMA: one C quadrant x K=64
#define MM(MH,NH,BB) { _Pragma("unroll") for (int mf=0; mf<4; mf++) _Pragma("unroll") for (int nf=0; nf<2; nf++){ \
    acc[(MH)*4+mf][(NH)*2+nf]=__builtin_amdgcn_mfma_f32_16x16x32_bf16(a[mf][0],BB[nf][0],acc[(MH)*4+mf][(NH)*2+nf],0,0,0); \
    acc[(MH)*4+mf][(NH)*2+nf]=__builtin_amdgcn_mfma_f32_16x16x32_bf16(a[mf][1],BB[nf][1],acc[(MH)*4+mf][(NH)*2+nf],0,0,0); } }
#define BAR   __builtin_amdgcn_s_barrier()
#define WLG0  asm volatile("s_waitcnt lgkmcnt(0)")
#define PRIO1 __builtin_amdgcn_s_setprio(1)
#define PRIO0 __builtin_amdgcn_s_setprio(0)

  // prologue: tile0 -> buf0 (4 granules), vmcnt(4), tile1 -> buf1 (3 granules), vmcnt(6)
  STG(sA0,sA1,dA0,dA1,0,0,0,ldaL);
  STG(sB0,sB1,dB0,dB1,0,0,0,ldbL);
  STG(sA0,sA1,dA0,dA1,0,1,0,ldaL);
  STG(sB0,sB1,dB0,dB1,0,1,0,ldbL);
  asm volatile("s_waitcnt vmcnt(4)");
  STG(sA0,sA1,dA0,dA1,16384,0,1,ldaL);
  STG(sB0,sB1,dB0,dB1,16384,0,1,ldbL);
  STG(sA0,sA1,dA0,dA1,16384,1,1,ldaL);
  asm volatile("s_waitcnt vmcnt(6)");
  BAR;

  for (int i = 0; i < NI; i++) {
    const int t1 = 2*i + 1;                                  // always < NT
    const int t2 = (2*i + 2 < NT) ? 2*i + 2 : NT - 1;        // clamped prefetch
    const int t3 = (2*i + 3 < NT) ? 2*i + 3 : NT - 1;

    // P1: read buf0 A-h0 (8) + B-h0 (4); stage buf1 B-g1 (tile t1)
    LDA(0,0); LDB(b0,0,0);
    STG(sB0,sB1,dB0,dB1,16384,1,t1,ldbL);
    asm volatile("s_waitcnt lgkmcnt(8)");
    BAR; WLG0; PRIO1; MM(0,0,b0); PRIO0; BAR;

    // P2: read buf0 B-h1 (4); stage buf0 A-g0 (tile t2)
    LDB(b1,0,1);
    STG(sA0,sA1,dA0,dA1,0,0,t2,ldaL);
    BAR; WLG0; PRIO1; MM(0,1,b1); PRIO0; BAR;

    // P3: read buf0 A-h1 (8); stage buf0 B-g0 (tile t2)
    LDA(0,1);
    STG(sB0,sB1,dB0,dB1,0,0,t2,ldbL);
    BAR; WLG0; PRIO1; MM(1,1,b1); PRIO0; BAR;

    // P4: no reads (b0 held); stage buf0 A-g1 (tile t2); counted vmcnt, never 0
    STG(sA0,sA1,dA0,dA1,0,1,t2,ldaL);
    BAR; WLG0; PRIO1; MM(1,0,b0); PRIO0;
    asm volatile("s_waitcnt vmcnt(6)");
    BAR;

    // P5: read buf1 A-h0 + B-h0; stage buf0 B-g1 (tile t2)
    LDA(2048,0); LDB(b0,2048,0);
    STG(sB0,sB1,dB0,dB1,0,1,t2,ldbL);
    asm volatile("s_waitcnt lgkmcnt(8)");
    BAR; WLG0; PRIO1; MM(0,0,b0); PRIO0; BAR;

    // P6: read buf1 B-h1; stage buf1 A-g0 (tile t3)
    LDB(b1,2048,1);
    STG(sA0,sA1,dA0,dA1,16384,0,t3,ldaL);
    BAR; WLG0; PRIO1; MM(0,1,b1); PRIO0; BAR;

    // P7: read buf1 A-h1; stage buf1 B-g0 (tile t3)
    LDA(2048,1);
    STG(sB0,sB1,dB0,dB1,16384,0,t3,ldbL);
    BAR; WLG0; PRIO1; MM(1,1,b1); PRIO0; BAR;

    // P8: no reads; stage buf1 A-g1 (tile t3); counted vmcnt
    STG(sA0,sA1,dA0,dA1,16384,1,t3,ldaL);
    BAR; WLG0; PRIO1; MM(1,0,b0); PRIO0;
    asm volatile("s_waitcnt vmcnt(6)");
    BAR;
  }

  asm volatile("s_waitcnt vmcnt(0)");   // drain dangling clamped prefetches

#undef STG
#undef LDA
#undef LDB
#undef MM
#undef BAR
#undef WLG0
#undef PRIO1
#undef PRIO0

  // epilogue: C/D layout: n = la, m = quad*4 + reg   [measured m89/m91]
  float* Cf = (float*)Cout + (long)bz * sC;
  unsigned short* Ch = (unsigned short*)Cout + (long)bz * sC;
  #pragma unroll
  for (int mf = 0; mf < 8; mf++) {
    #pragma unroll
    for (int nf = 0; nf < 4; nf++) {
      #pragma unroll
      for (int r = 0; r < 4; r++) {
        long m = m0 + wm * 128 + mf * 16 + quad * 4 + r;
        long n = n0 + wn * 64  + nf * 16 + la;
        float v = acc[mf][nf][r] * alpha;
        if (BIASN) v += bias[n];
        long idx = m * (long)ldc + n;
        if (OUTF) Cf[idx] = v;
        else      Ch[idx] = f2bf(v);
      }
    }
  }
}

// ---------------- row softmax (in-place, bf16) ----------------
__global__ __launch_bounds__(256) void softmax_rows(unsigned short* __restrict__ S, int cols){
  long row = blockIdx.x;
  unsigned short* p = S + row * (long)cols;
  int tid  = threadIdx.x;
  int wave = tid >> 6;
  int lane = tid & 63;

  uint4 raw = ((const uint4*)p)[tid];   // 8 bf16
  unsigned short* rs = (unsigned short*)&raw;
  float x[8];
  float mx = -1e30f;
  #pragma unroll
  for (int i = 0; i < 8; i++) { x[i] = bf2f(rs[i]); mx = fmaxf(mx, x[i]); }
  #pragma unroll
  for (int off = 32; off >= 1; off >>= 1) mx = fmaxf(mx, __shfl_xor(mx, off, 64));

  __shared__ float smax[4], ssum[4];
  if (lane == 0) smax[wave] = mx;
  __syncthreads();
  mx = fmaxf(fmaxf(smax[0], smax[1]), fmaxf(smax[2], smax[3]));

  float s = 0.0f;
  #pragma unroll
  for (int i = 0; i < 8; i++) { x[i] = __expf(x[i] - mx); s += x[i]; }
  #pragma unroll
  for (int off = 32; off >= 1; off >>= 1) s += __shfl_xor(s, off, 64);
  if (lane == 0) ssum[wave] = s;
  __syncthreads();
  s = ssum[0] + ssum[1] + ssum[2] + ssum[3];
  float inv = 1.0f / s;

  #pragma unroll
  for (int i = 0; i < 8; i++) rs[i] = f2bf(x[i] * inv);
  ((uint4*)p)[tid] = raw;
}

// ---------------- launch ----------------

extern "C" void kernel_launch(void* const* d_in, const int* in_sizes, int n_in,
                              void* d_out, int out_size, void* d_ws, size_t ws_size,
                              hipStream_t stream)
{
  const float* x  = (const float*)d_in[0];
  const float* Wq = (const float*)d_in[1];
  const float* bq = (const float*)d_in[2];
  const float* Wk = (const float*)d_in[3];
  const float* bk = (const float*)d_in[4];
  const float* Wv = (const float*)d_in[5];
  const float* bv = (const float*)d_in[6];
  const float* Wo = (const float*)d_in[7];
  const float* bo = (const float*)d_in[8];

  const int B = 8, S = 2048, E = 768;
  const int F = 3 * E;           // 2304 fused output features
  const long BS = (long)B * S;   // 16384

  char* ws = (char*)d_ws;
  unsigned short* x_bf = (unsigned short*)ws;  ws += BS * E * 2;       // 25.2 MB (also ctx)
  unsigned short* W3t  = (unsigned short*)ws;  ws += (long)F * E * 2;  // 3.5 MB  [2304][768]
  unsigned short* Wot  = (unsigned short*)ws;  ws += (long)E * E * 2;
  float*          bqkv = (float*)ws;           ws += 16384;            // 2304 floats (padded)
  unsigned short* QKVb = (unsigned short*)ws;  ws += BS * F * 2;       // 75.5 MB [16384][2304]
  unsigned short* Vt   = (unsigned short*)ws;  ws += BS * E * 2;       // 25.2 MB [B][E][S]
  unsigned short* Sb   = (unsigned short*)ws;  ws += (long)B * S * S * 2; // 67.1 MB
  unsigned short* Cx   = x_bf;  // ctx aliases x_bf (x_bf dead after QKV gemm)

  if (ws_size < (size_t)((char*)ws - (char*)d_ws)) return;

  const float rsE = 1.0f / sqrtf((float)E);

  cast_f32_bf16<<<(int)((BS * E) / 1024), 256, 0, stream>>>(x, x_bf, BS * E);
  dim3 tg(E / 64, E / 64);
  transpose_cast_w<<<tg, 256, 0, stream>>>(Wq, W3t,                 E);
  transpose_cast_w<<<tg, 256, 0, stream>>>(Wk, W3t + (long)E * E,   E);
  transpose_cast_w<<<tg, 256, 0, stream>>>(Wv, W3t + (long)2*E * E, E);
  transpose_cast_w<<<tg, 256, 0, stream>>>(Wo, Wot, E);
  hipMemcpyAsync(bqkv,         bq, E * sizeof(float), hipMemcpyDeviceToDevice, stream);
  hipMemcpyAsync(bqkv + E,     bk, E * sizeof(float), hipMemcpyDeviceToDevice, stream);
  hipMemcpyAsync(bqkv + 2 * E, bv, E * sizeof(float), hipMemcpyDeviceToDevice, stream);

  // fused QKV = x @ [Wq|Wk|Wv] + [bq|bk|bv] : M=16384 N=2304 K=768, grid 9x64=576
  dim3 gf(F / 256, (int)(BS / 256), 1);
  gemm256<0,1,0><<<gf, 512, 0, stream>>>(x_bf, W3t, QKVb, bqkv,
                                         (int)BS, F, E, E, E, F,
                                         0, 0, 0, 1.0f);

  // Vt[b][e][s] from the V slice of QKVb (cols 1536..2303)
  dim3 gt(S / 128, E / 128, B);
  vtrans<<<gt, 256, 0, stream>>>(QKVb + 2 * E, Vt);

  // Sb = Q K^T / sqrt(E) : Q,K strided views of QKVb (lda=ldb=2304), grid 8x8x8=512
  dim3 gs(S / 256, S / 256, B);
  gemm256<1,0,0><<<gs, 512, 0, stream>>>(QKVb, QKVb + E, Sb, nullptr,
                                         S, S, E, F, F, S,
                                         (long)S * F, (long)S * F, (long)S * S, rsE);

  softmax_rows<<<(int)BS, 256, 0, stream>>>(Sb, S);

  // ctx = softmax(S) @ V : M=2048 N=768 K=2048, grid 3x8x8 = 192
  dim3 gp(E / 256, S / 256, B);
  gemm256<2,0,0><<<gp, 512, 0, stream>>>(Sb, Vt, Cx, nullptr,
                                         S, E, S, S, S, E,
                                         (long)S * S, (long)E * S, (long)S * E, 1.0f);

  // out = ctx @ Wo + bo (fp32 out) : grid 3x64 = 192
  dim3 g1(E / 256, (int)(BS / 256), 1);
  gemm256<3,1,1><<<g1, 512, 0, stream>>>(Cx, Wot, (float*)d_out, bo,
                                         (int)BS, E, E, E, E, E,
                                         0, 0, 0, 1.0f);
}

// Round 3
// 355.512 us; speedup vs baseline: 1.4647x; 1.2494x over previous
//
#include <hip/hip_runtime.h>
#include <hip/hip_bf16.h>

// Single-head self-attention, B=8 S=2048 E=768, fp32 in/out.
// R7: R6's 256x256 8-phase GEMM plus:
//   - V-transpose fused into QKV epilogue (blocks n0>=1536 write Vt[B][E][S]
//     via XOR-swizzled LDS transpose; vtrans kernel + 25MB dead write removed)
//   - sched_barrier(0) fences pinning each MFMA cluster between its
//     lgkmcnt(0) and closing s_barrier (hipcc can hoist register-only MFMA
//     across inline-asm waitcnts - rule #18 failure mode)
//   - 4 weight transposes merged into one launch (grid z=4)
// Schedule (8-phase, counted vmcnt(6), setprio, XCD swizzle) unchanged.

using short8  = __attribute__((ext_vector_type(8))) short;
using floatx4 = __attribute__((ext_vector_type(4))) float;

typedef const __attribute__((address_space(1))) unsigned short* gas_us;
typedef __attribute__((address_space(3))) unsigned short* las_us;

__device__ __forceinline__ float bf2f(unsigned short u){
  union { unsigned int i; float f; } v; v.i = ((unsigned int)u) << 16; return v.f;
}
__device__ __forceinline__ unsigned short f2bf(float f){
  union { float f; unsigned int i; } v; v.f = f;
  unsigned int r = v.i + 0x7fffu + ((v.i >> 16) & 1u);   // RNE
  return (unsigned short)(r >> 16);
}

// ---------------- prep kernels ----------------

__global__ __launch_bounds__(256) void cast_f32_bf16(const float* __restrict__ in,
                                                     unsigned short* __restrict__ out,
                                                     long n){
  long i = ((long)blockIdx.x * 256 + threadIdx.x) * 4;
  if (i + 3 < n) {
    float4 v = *(const float4*)(in + i);
    uint2 o;
    o.x = (unsigned int)f2bf(v.x) | ((unsigned int)f2bf(v.y) << 16);
    o.y = (unsigned int)f2bf(v.z) | ((unsigned int)f2bf(v.w) << 16);
    *(uint2*)(out + i) = o;
  }
}

// 4 weight matrices [n x n] fp32 row-major -> bf16 transposed, one launch.
__global__ __launch_bounds__(256) void transpose_cast_w4(
    const float* __restrict__ W0, const float* __restrict__ W1,
    const float* __restrict__ W2, const float* __restrict__ W3,
    unsigned short* __restrict__ D0, unsigned short* __restrict__ D1,
    unsigned short* __restrict__ D2, unsigned short* __restrict__ D3, int n){
  __shared__ float tile[64][65];
  const int z = blockIdx.z;
  const float* W = (z == 0) ? W0 : (z == 1) ? W1 : (z == 2) ? W2 : W3;
  unsigned short* Wt = (z == 0) ? D0 : (z == 1) ? D1 : (z == 2) ? D2 : D3;
  int bx = blockIdx.x * 64;     // f base
  int by = blockIdx.y * 64;     // e base
  int tx = threadIdx.x & 63;
  int ty = threadIdx.x >> 6;    // 0..3
  #pragma unroll
  for (int r = ty; r < 64; r += 4)
    tile[r][tx] = W[(long)(by + r) * n + bx + tx];
  __syncthreads();
  #pragma unroll
  for (int r = ty; r < 64; r += 4)
    Wt[(long)(bx + r) * n + by + tx] = f2bf(tile[tx][r]);
}

// ---------------- 256x256 8-phase MFMA GEMM ----------------
// C[m,n] = alpha * sum_k A[m,k]*Bt[n,k]  (+ bias[n])
// A  : bf16 [M x K] rows stride lda elements (batch stride sA)
// Bt : bf16 [N x K] rows stride ldb elements (batch stride sB)
// C  : bf16 or fp32 (OUTF), ldc leading dim (batch stride sC)
// VTFUSE: blocks with n0>=1536 write transposed to vt[B=2048-row batches].
// Requires: M,N multiples of 256; K multiple of 128; grid product % 8 == 0.

union SMemU {
  struct { unsigned short A[2 * 256 * 64]; unsigned short B[2 * 256 * 64]; } ab;
  unsigned short T[256 * 256];
};

template<int TAG, int BIASN, int OUTF, int VTFUSE>
__global__ __launch_bounds__(512, 2) void gemm256(
    const unsigned short* __restrict__ A,
    const unsigned short* __restrict__ Bt,
    void* __restrict__ Cout,
    const float* __restrict__ bias,
    unsigned short* __restrict__ vt,
    int M, int N, int K, int lda, int ldb, int ldc,
    long sA, long sB, long sC, float alpha)
{
  // --- XCD-aware bijective swizzle of flattened block id (nwg % 8 == 0) ---
  const int gx = gridDim.x, gy = gridDim.y;
  const int nxy = gx * gy;
  const int nwg = nxy * (int)gridDim.z;
  int flat = (int)blockIdx.x + gx * (int)blockIdx.y + nxy * (int)blockIdx.z;
  if (!(nwg & 7)) flat = (flat & 7) * (nwg >> 3) + (flat >> 3);
  const int bz  = flat / nxy;
  const int rxy = flat - bz * nxy;
  const int by  = rxy / gx;
  const int bx  = rxy - by * gx;

  A  += (long)bz * sA;
  Bt += (long)bz * sB;

  __shared__ __align__(16) SMemU sm;
  unsigned short* Asm = sm.ab.A;
  unsigned short* Bsm = sm.ab.B;

  const int tid  = threadIdx.x;
  const int l    = tid & 63;
  const int wv   = tid >> 6;        // 0..7
  const int wm   = wv >> 2;         // 0..1  (M half of block)
  const int wn   = wv & 3;          // 0..3  (N quarter)
  const int la   = l & 15;
  const int quad = l >> 4;
  const int c0   = quad ^ (l & 7);  // swizzled chunk (row&7 == la&7)

  const long m0 = (long)by * 256;
  const long n0 = (long)bx * 256;
  const long ldaL = lda, ldbL = ldb;

  // staging: granule g of a 256-row tile = rows {g*64..+63} U {128+g*64..+63};
  // wave wv, instr j stages 8 rows at r_loc = wv*16 + j*8 within the granule.
  const int r8  = l >> 3;                 // 0..7
  const int cg  = (l & 7) ^ r8;           // pre-swizzled global chunk
  const int st0 = wv * 16, st1 = wv * 16 + 8;
  const int ar0 = (st0 >> 6) * 128 + (st0 & 63);
  const int ar1 = (st1 >> 6) * 128 + (st1 & 63);

  const unsigned short* sA0 = A  + (m0 + ar0 + r8) * ldaL + cg * 8;
  const unsigned short* sA1 = A  + (m0 + ar1 + r8) * ldaL + cg * 8;
  const unsigned short* sB0 = Bt + (n0 + ar0 + r8) * ldbL + cg * 8;
  const unsigned short* sB1 = Bt + (n0 + ar1 + r8) * ldbL + cg * 8;

  las_us dA0 = (las_us)&Asm[ar0 * 64];
  las_us dA1 = (las_us)&Asm[ar1 * 64];
  las_us dB0 = (las_us)&Bsm[ar0 * 64];
  las_us dB1 = (las_us)&Bsm[ar1 * 64];

  const short8* A8 = (const short8*)Asm;   // tile stride 2048 short8
  const short8* B8 = (const short8*)Bsm;
  const int rA = (wm * 128 + la) * 8;
  const int rB = (wn * 64  + la) * 8;

  floatx4 acc[8][4];
  #pragma unroll
  for (int i = 0; i < 8; i++)
    #pragma unroll
    for (int j = 0; j < 4; j++)
      #pragma unroll
      for (int r = 0; r < 4; r++) acc[i][j][r] = 0.0f;

  short8 a[4][2], b0[2][2], b1[2][2];

  const int NT = K >> 6;   // K % 128 == 0 so NT even
  const int NI = NT >> 1;

// stage one 128-row granule (2 x global_load_lds, 16B/lane, linear LDS dest)
#define STG(P0,P1,D0,D1,BO,G,KT,LD) do{ const long _ko=(long)(G)*64*(LD)+(long)(KT)*64; \
  __builtin_amdgcn_global_load_lds((gas_us)((P0)+_ko),(D0)+(BO)+(G)*4096,16,0,0);       \
  __builtin_amdgcn_global_load_lds((gas_us)((P1)+_ko),(D1)+(BO)+(G)*4096,16,0,0);}while(0)
// ds_read_b128 fragment loads; BO in short8 units (0 or 2048)
#define LDA(BO,MH) { _Pragma("unroll") for (int mf=0; mf<4; mf++){ \
    a[mf][0]=A8[(BO)+rA+((MH)*4+mf)*128+c0]; a[mf][1]=A8[(BO)+rA+((MH)*4+mf)*128+(c0^4)]; } }
#define LDB(DST,BO,NH) { _Pragma("unroll") for (int nf=0; nf<2; nf++){ \
    DST[nf][0]=B8[(BO)+rB+((NH)*2+nf)*128+c0]; DST[nf][1]=B8[(BO)+rB+((NH)*2+nf)*128+(c0^4)]; } }
// 16 MFMA: one C quadrant x K=64
#define MM(MH,NH,BB) { _Pragma("unroll") for (int mf=0; mf<4; mf++) _Pragma("unroll") for (int nf=0; nf<2; nf++){ \
    acc[(MH)*4+mf][(NH)*2+nf]=__builtin_amdgcn_mfma_f32_16x16x32_bf16(a[mf][0],BB[nf][0],acc[(MH)*4+mf][(NH)*2+nf],0,0,0); \
    acc[(MH)*4+mf][(NH)*2+nf]=__builtin_amdgcn_mfma_f32_16x16x32_bf16(a[mf][1],BB[nf][1],acc[(MH)*4+mf][(NH)*2+nf],0,0,0); } }
#define BAR   __builtin_amdgcn_s_barrier()
#define WLG0  asm volatile("s_waitcnt lgkmcnt(0)")
#define SFEN  __builtin_amdgcn_sched_barrier(0)
#define PRIO1 __builtin_amdgcn_s_setprio(1)
#define PRIO0 __builtin_amdgcn_s_setprio(0)

  // prologue: tile0 -> buf0 (4 granules), vmcnt(4), tile1 -> buf1 (3 granules), vmcnt(6)
  STG(sA0,sA1,dA0,dA1,0,0,0,ldaL);
  STG(sB0,sB1,dB0,dB1,0,0,0,ldbL);
  STG(sA0,sA1,dA0,dA1,0,1,0,ldaL);
  STG(sB0,sB1,dB0,dB1,0,1,0,ldbL);
  asm volatile("s_waitcnt vmcnt(4)");
  STG(sA0,sA1,dA0,dA1,16384,0,1,ldaL);
  STG(sB0,sB1,dB0,dB1,16384,0,1,ldbL);
  STG(sA0,sA1,dA0,dA1,16384,1,1,ldaL);
  asm volatile("s_waitcnt vmcnt(6)");
  BAR;

  for (int i = 0; i < NI; i++) {
    const int t1 = 2*i + 1;                                  // always < NT
    const int t2 = (2*i + 2 < NT) ? 2*i + 2 : NT - 1;        // clamped prefetch
    const int t3 = (2*i + 3 < NT) ? 2*i + 3 : NT - 1;

    // P1: read buf0 A-h0 (8) + B-h0 (4); stage buf1 B-g1 (tile t1)
    LDA(0,0); LDB(b0,0,0);
    STG(sB0,sB1,dB0,dB1,16384,1,t1,ldbL);
    asm volatile("s_waitcnt lgkmcnt(8)");
    BAR; WLG0; SFEN; PRIO1; MM(0,0,b0); PRIO0; SFEN; BAR;

    // P2: read buf0 B-h1 (4); stage buf0 A-g0 (tile t2)
    LDB(b1,0,1);
    STG(sA0,sA1,dA0,dA1,0,0,t2,ldaL);
    BAR; WLG0; SFEN; PRIO1; MM(0,1,b1); PRIO0; SFEN; BAR;

    // P3: read buf0 A-h1 (8); stage buf0 B-g0 (tile t2)
    LDA(0,1);
    STG(sB0,sB1,dB0,dB1,0,0,t2,ldbL);
    BAR; WLG0; SFEN; PRIO1; MM(1,1,b1); PRIO0; SFEN; BAR;

    // P4: no reads (b0 held); stage buf0 A-g1 (tile t2); counted vmcnt, never 0
    STG(sA0,sA1,dA0,dA1,0,1,t2,ldaL);
    BAR; WLG0; SFEN; PRIO1; MM(1,0,b0); PRIO0; SFEN;
    asm volatile("s_waitcnt vmcnt(6)");
    BAR;

    // P5: read buf1 A-h0 + B-h0; stage buf0 B-g1 (tile t2)
    LDA(2048,0); LDB(b0,2048,0);
    STG(sB0,sB1,dB0,dB1,0,1,t2,ldbL);
    asm volatile("s_waitcnt lgkmcnt(8)");
    BAR; WLG0; SFEN; PRIO1; MM(0,0,b0); PRIO0; SFEN; BAR;

    // P6: read buf1 B-h1; stage buf1 A-g0 (tile t3)
    LDB(b1,2048,1);
    STG(sA0,sA1,dA0,dA1,16384,0,t3,ldaL);
    BAR; WLG0; SFEN; PRIO1; MM(0,1,b1); PRIO0; SFEN; BAR;

    // P7: read buf1 A-h1; stage buf1 B-g0 (tile t3)
    LDA(2048,1);
    STG(sB0,sB1,dB0,dB1,16384,0,t3,ldbL);
    BAR; WLG0; SFEN; PRIO1; MM(1,1,b1); PRIO0; SFEN; BAR;

    // P8: no reads; stage buf1 A-g1 (tile t3); counted vmcnt
    STG(sA0,sA1,dA0,dA1,16384,1,t3,ldaL);
    BAR; WLG0; SFEN; PRIO1; MM(1,0,b0); PRIO0; SFEN;
    asm volatile("s_waitcnt vmcnt(6)");
    BAR;
  }

  asm volatile("s_waitcnt vmcnt(0)");   // drain dangling clamped prefetches

#undef STG
#undef LDA
#undef LDB
#undef MM
#undef BAR
#undef WLG0
#undef SFEN
#undef PRIO1
#undef PRIO0

  // ---- V-fused epilogue: transpose 256x256 tile through LDS -> Vt[B][E][S]
  if (VTFUSE && n0 >= 1536) {
    __syncthreads();                 // all waves past their LDS reads + DMA drained
    unsigned short* T = sm.T;        // [256][256], XOR-swizzled columns
    #pragma unroll
    for (int mf = 0; mf < 8; mf++) {
      #pragma unroll
      for (int nf = 0; nf < 4; nf++) {
        const int ln = wn * 64 + nf * 16 + la;          // local n (Vt row)
        const int lm = wm * 128 + mf * 16 + quad * 4;   // local m (Vt col base)
        unsigned long long pk = 0;
        #pragma unroll
        for (int r = 0; r < 4; r++) {
          float v = acc[mf][nf][r] * alpha;
          if (BIASN) v += bias[n0 + ln];
          pk |= (unsigned long long)f2bf(v) << (16 * r);
        }
        *(unsigned long long*)&T[ln * 256 + (lm ^ ((ln & 7) << 3))] = pk;
      }
    }
    __syncthreads();
    const int b  = (int)(m0 >> 11);          // batch (2048 tokens each)
    const int s0 = (int)(m0 & 2047);
    const int e0 = (int)(n0 - 1536);
    unsigned short* dst = vt + (long)b * 768 * 2048 + (long)e0 * 2048 + s0;
    const int lr = tid >> 5;                 // 0..15
    const int c  = tid & 31;                 // 16B chunk within row
    #pragma unroll
    for (int i = 0; i < 16; i++) {
      const int ln = i * 16 + lr;
      short8 v = *(const short8*)&T[ln * 256 + ((c * 8) ^ ((ln & 7) << 3))];
      *(short8*)&dst[(long)ln * 2048 + c * 8] = v;
    }
    return;
  }

  // epilogue: C/D layout: n = la, m = quad*4 + reg   [measured m89/m91]
  float* Cf = (float*)Cout + (long)bz * sC;
  unsigned short* Ch = (unsigned short*)Cout + (long)bz * sC;
  #pragma unroll
  for (int mf = 0; mf < 8; mf++) {
    #pragma unroll
    for (int nf = 0; nf < 4; nf++) {
      #pragma unroll
      for (int r = 0; r < 4; r++) {
        long m = m0 + wm * 128 + mf * 16 + quad * 4 + r;
        long n = n0 + wn * 64  + nf * 16 + la;
        float v = acc[mf][nf][r] * alpha;
        if (BIASN) v += bias[n];
        long idx = m * (long)ldc + n;
        if (OUTF) Cf[idx] = v;
        else      Ch[idx] = f2bf(v);
      }
    }
  }
}

// ---------------- row softmax (in-place, bf16) ----------------
__global__ __launch_bounds__(256) void softmax_rows(unsigned short* __restrict__ S, int cols){
  long row = blockIdx.x;
  unsigned short* p = S + row * (long)cols;
  int tid  = threadIdx.x;
  int wave = tid >> 6;
  int lane = tid & 63;

  uint4 raw = ((const uint4*)p)[tid];   // 8 bf16
  unsigned short* rs = (unsigned short*)&raw;
  float x[8];
  float mx = -1e30f;
  #pragma unroll
  for (int i = 0; i < 8; i++) { x[i] = bf2f(rs[i]); mx = fmaxf(mx, x[i]); }
  #pragma unroll
  for (int off = 32; off >= 1; off >>= 1) mx = fmaxf(mx, __shfl_xor(mx, off, 64));

  __shared__ float smax[4], ssum[4];
  if (lane == 0) smax[wave] = mx;
  __syncthreads();
  mx = fmaxf(fmaxf(smax[0], smax[1]), fmaxf(smax[2], smax[3]));

  float s = 0.0f;
  #pragma unroll
  for (int i = 0; i < 8; i++) { x[i] = __expf(x[i] - mx); s += x[i]; }
  #pragma unroll
  for (int off = 32; off >= 1; off >>= 1) s += __shfl_xor(s, off, 64);
  if (lane == 0) ssum[wave] = s;
  __syncthreads();
  s = ssum[0] + ssum[1] + ssum[2] + ssum[3];
  float inv = 1.0f / s;

  #pragma unroll
  for (int i = 0; i < 8; i++) rs[i] = f2bf(x[i] * inv);
  ((uint4*)p)[tid] = raw;
}

// ---------------- launch ----------------

extern "C" void kernel_launch(void* const* d_in, const int* in_sizes, int n_in,
                              void* d_out, int out_size, void* d_ws, size_t ws_size,
                              hipStream_t stream)
{
  const float* x  = (const float*)d_in[0];
  const float* Wq = (const float*)d_in[1];
  const float* bq = (const float*)d_in[2];
  const float* Wk = (const float*)d_in[3];
  const float* bk = (const float*)d_in[4];
  const float* Wv = (const float*)d_in[5];
  const float* bv = (const float*)d_in[6];
  const float* Wo = (const float*)d_in[7];
  const float* bo = (const float*)d_in[8];

  const int B = 8, S = 2048, E = 768;
  const int F = 3 * E;           // 2304 fused output features
  const long BS = (long)B * S;   // 16384

  char* ws = (char*)d_ws;
  unsigned short* x_bf = (unsigned short*)ws;  ws += BS * E * 2;       // 25.2 MB (also ctx)
  unsigned short* W3t  = (unsigned short*)ws;  ws += (long)F * E * 2;  // 3.5 MB  [2304][768]
  unsigned short* Wot  = (unsigned short*)ws;  ws += (long)E * E * 2;
  float*          bqkv = (float*)ws;           ws += 16384;            // 2304 floats (padded)
  unsigned short* QKVb = (unsigned short*)ws;  ws += BS * F * 2;       // 75.5 MB [16384][2304]
  unsigned short* Vt   = (unsigned short*)ws;  ws += BS * E * 2;       // 25.2 MB [B][E][S]
  unsigned short* Sb   = (unsigned short*)ws;  ws += (long)B * S * S * 2; // 67.1 MB
  unsigned short* Cx   = x_bf;  // ctx aliases x_bf (x_bf dead after QKV gemm)

  if (ws_size < (size_t)((char*)ws - (char*)d_ws)) return;

  const float rsE = 1.0f / sqrtf((float)E);

  cast_f32_bf16<<<(int)((BS * E) / 1024), 256, 0, stream>>>(x, x_bf, BS * E);
  dim3 tg(E / 64, E / 64, 4);
  transpose_cast_w4<<<tg, 256, 0, stream>>>(Wq, Wk, Wv, Wo,
                                            W3t, W3t + (long)E * E, W3t + (long)2 * E * E, Wot, E);
  hipMemcpyAsync(bqkv,         bq, E * sizeof(float), hipMemcpyDeviceToDevice, stream);
  hipMemcpyAsync(bqkv + E,     bk, E * sizeof(float), hipMemcpyDeviceToDevice, stream);
  hipMemcpyAsync(bqkv + 2 * E, bv, E * sizeof(float), hipMemcpyDeviceToDevice, stream);

  // fused QKV = x @ [Wq|Wk|Wv] + [bq|bk|bv] : M=16384 N=2304 K=768, grid 9x64=576
  // V-slice (n0>=1536) written transposed to Vt by the fused epilogue.
  dim3 gf(F / 256, (int)(BS / 256), 1);
  gemm256<0,1,0,1><<<gf, 512, 0, stream>>>(x_bf, W3t, QKVb, bqkv, Vt,
                                           (int)BS, F, E, E, E, F,
                                           0, 0, 0, 1.0f);

  // Sb = Q K^T / sqrt(E) : Q,K strided views of QKVb (lda=ldb=2304), grid 8x8x8=512
  dim3 gs(S / 256, S / 256, B);
  gemm256<1,0,0,0><<<gs, 512, 0, stream>>>(QKVb, QKVb + E, Sb, nullptr, nullptr,
                                           S, S, E, F, F, S,
                                           (long)S * F, (long)S * F, (long)S * S, rsE);

  softmax_rows<<<(int)BS, 256, 0, stream>>>(Sb, S);

  // ctx = softmax(S) @ V : M=2048 N=768 K=2048, grid 3x8x8 = 192
  dim3 gp(E / 256, S / 256, B);
  gemm256<2,0,0,0><<<gp, 512, 0, stream>>>(Sb, Vt, Cx, nullptr, nullptr,
                                           S, E, S, S, S, E,
                                           (long)S * S, (long)E * S, (long)S * E, 1.0f);

  // out = ctx @ Wo + bo (fp32 out) : grid 3x64 = 192
  dim3 g1(E / 256, (int)(BS / 256), 1);
  gemm256<3,1,1,0><<<g1, 512, 0, stream>>>(Cx, Wot, (float*)d_out, bo, nullptr,
                                           (int)BS, E, E, E, E, E,
                                           0, 0, 0, 1.0f);
}